// Round 1
// baseline (111.271 us; speedup 1.0000x reference)
//
#include <hip/hip_runtime.h>
#include <math.h>

constexpr int NROWS = 524288;
constexpr int DLAT  = 64;
constexpr float PI_F = 3.14159265358979323846f;

// ws layout: acc[0]=rot_sq_sum, acc[1]=trans_sq_sum, acc[2]=latent_sq_sum (doubles)

__global__ void init_acc_kernel(double* acc) {
    if (threadIdx.x < 3) acc[threadIdx.x] = 0.0;
}

__device__ __forceinline__ void euler_to_quat(float p0, float p1, float p2, float q[4]) {
    float sr, cr, sp, cp, sy, cy;
    sincosf(p0 * 0.5f, &sr, &cr);
    sincosf(p1 * 0.5f, &sp, &cp);
    sincosf(p2 * 0.5f, &sy, &cy);
    q[0] = sr * cp * cy - cr * sp * sy;
    q[1] = cr * sp * cy + sr * cp * sy;
    q[2] = cr * cp * sy - sr * sp * cy;
    q[3] = cr * cp * cy + sr * sp * sy;
}

// R = Rz2(t) * Rx(e) * Rz(a), a=-r0, e=pi/2+r1, t=-r2  (closed form)
__device__ __forceinline__ void rot_mat(float r0, float r1, float r2, float R[9]) {
    float sa, ca, se, ce, st, ct;
    sincosf(-r0, &sa, &ca);
    sincosf(1.57079632679489662f + r1, &se, &ce);
    sincosf(-r2, &st, &ct);
    R[0] =  ct * ca - st * ce * sa;
    R[1] = -ct * sa - st * ce * ca;
    R[2] =  st * se;
    R[3] =  st * ca + ct * ce * sa;
    R[4] = -st * sa + ct * ce * ca;
    R[5] = -ct * se;
    R[6] =  se * sa;
    R[7] =  se * ca;
    R[8] =  ce;
}

__global__ __launch_bounds__(256) void crit_main_kernel(
    const float* __restrict__ pose_pred, const float* __restrict__ pose_gt,
    const float* __restrict__ trans_pred, const float* __restrict__ trans_gt,
    const float* __restrict__ latent_pred, const float* __restrict__ latent_gt,
    float* __restrict__ out, double* __restrict__ acc)
{
    const int tid      = blockIdx.x * blockDim.x + threadIdx.x;
    const int nthreads = gridDim.x * blockDim.x;

    float rot_s = 0.0f, trans_s = 0.0f, lat_s = 0.0f;

    // ---- phase A: per-row pose/trans work ----
    for (int i = tid; i < NROWS; i += nthreads) {
        const float pp0 = pose_pred[3*i + 0] * PI_F;
        const float pp1 = pose_pred[3*i + 1] * PI_F;
        const float pp2 = pose_pred[3*i + 2] * PI_F;
        const float pg0 = pose_gt[3*i + 0] * PI_F;
        const float pg1 = pose_gt[3*i + 1] * PI_F;
        const float pg2 = pose_gt[3*i + 2] * PI_F;

        // quaternion MSE partial
        float qp[4], qg[4];
        euler_to_quat(pp0, pp1, pp2, qp);
        euler_to_quat(pg0, pg1, pg2, qg);
        #pragma unroll
        for (int k = 0; k < 4; ++k) {
            float d = qp[k] - qg[k];
            rot_s += d * d;
        }

        // geodesic rotation distance
        float Rp[9], Rg[9];
        rot_mat(pp0, pp1, pp2, Rp);
        rot_mat(pg0, pg1, pg2, Rg);
        float tr = 0.0f;
        #pragma unroll
        for (int k = 0; k < 9; ++k) tr += Rp[k] * Rg[k];
        float c = fminf(1.0f, fmaxf(-1.0f, (tr - 1.0f) * 0.5f));
        out[3 + i] = acosf(c) * (180.0f / PI_F);

        // trans MSE partial + trans_distance
        const float tp0 = trans_pred[3*i + 0];
        const float tp1 = trans_pred[3*i + 1];
        const float tp2 = trans_pred[3*i + 2];
        const float tg0 = trans_gt[3*i + 0];
        const float tg1 = trans_gt[3*i + 1];
        const float tg2 = trans_gt[3*i + 2];
        float d0 = tp0 - tg0, d1 = tp1 - tg1, d2 = tp2 - tg2;
        trans_s += d0 * d0 + d1 * d1 + d2 * d2;
        float a1 = tg0 * tg1 - tp0 * tp1;
        float a2 = tg0 * tg2 - tp0 * tp2;
        out[3 + NROWS + i] = sqrtf(a1 * a1 + a2 * a2) * 100.0f;
    }

    // ---- phase B: latent MSE, vectorized float4 grid-stride ----
    const float4* __restrict__ lp = reinterpret_cast<const float4*>(latent_pred);
    const float4* __restrict__ lg = reinterpret_cast<const float4*>(latent_gt);
    const int nl4 = NROWS * DLAT / 4;
    for (int i = tid; i < nl4; i += nthreads) {
        float4 p = lp[i];
        float4 g = lg[i];
        float e0 = p.x - g.x, e1 = p.y - g.y, e2 = p.z - g.z, e3 = p.w - g.w;
        lat_s += e0 * e0 + e1 * e1 + e2 * e2 + e3 * e3;
    }

    // ---- block reduction (wave shuffle then LDS across 4 waves) ----
    #pragma unroll
    for (int off = 32; off > 0; off >>= 1) {
        rot_s   += __shfl_down(rot_s,   off, 64);
        trans_s += __shfl_down(trans_s, off, 64);
        lat_s   += __shfl_down(lat_s,   off, 64);
    }
    __shared__ float s_part[3][4];
    const int lane = threadIdx.x & 63;
    const int wave = threadIdx.x >> 6;
    if (lane == 0) {
        s_part[0][wave] = rot_s;
        s_part[1][wave] = trans_s;
        s_part[2][wave] = lat_s;
    }
    __syncthreads();
    if (threadIdx.x == 0) {
        float rb = s_part[0][0] + s_part[0][1] + s_part[0][2] + s_part[0][3];
        float tb = s_part[1][0] + s_part[1][1] + s_part[1][2] + s_part[1][3];
        float lb = s_part[2][0] + s_part[2][1] + s_part[2][2] + s_part[2][3];
        atomicAdd(&acc[0], (double)rb);
        atomicAdd(&acc[1], (double)tb);
        atomicAdd(&acc[2], (double)lb);
    }
}

__global__ void finalize_kernel(const double* __restrict__ acc, float* __restrict__ out) {
    if (threadIdx.x == 0) {
        out[0] = (float)(acc[0] / (4.0  * NROWS));
        out[1] = (float)(acc[1] / (3.0  * NROWS));
        out[2] = (float)(acc[2] / (64.0 * NROWS));
    }
}

extern "C" void kernel_launch(void* const* d_in, const int* in_sizes, int n_in,
                              void* d_out, int out_size, void* d_ws, size_t ws_size,
                              hipStream_t stream) {
    const float* pose_pred   = (const float*)d_in[0];
    const float* pose_gt     = (const float*)d_in[1];
    const float* trans_pred  = (const float*)d_in[2];
    const float* trans_gt    = (const float*)d_in[3];
    const float* latent_pred = (const float*)d_in[4];
    const float* latent_gt   = (const float*)d_in[5];
    float*  out = (float*)d_out;
    double* acc = (double*)d_ws;

    hipLaunchKernelGGL(init_acc_kernel, dim3(1), dim3(64), 0, stream, acc);
    hipLaunchKernelGGL(crit_main_kernel, dim3(2048), dim3(256), 0, stream,
                       pose_pred, pose_gt, trans_pred, trans_gt,
                       latent_pred, latent_gt, out, acc);
    hipLaunchKernelGGL(finalize_kernel, dim3(1), dim3(64), 0, stream, acc, out);
}

// Round 2
// 53.796 us; speedup vs baseline: 2.0684x; 2.0684x over previous
//
#include <hip/hip_runtime.h>
#include <math.h>

constexpr int NROWS = 524288;
constexpr int DLAT  = 64;
constexpr float PI_F = 3.14159265358979323846f;
constexpr int BLOCK = 256;
constexpr int PA_BLOCKS = 512;                       // 4 pose/trans rows per thread
constexpr int PB_BLOCKS = 1536;                      // latent streaming blocks
constexpr int TOTAL_BLOCKS = PA_BLOCKS + PB_BLOCKS;  // 2048

// d_ws layout (floats): part[0*T+b]=rot, part[1*T+b]=trans, part[2*T+b]=latent

__device__ __forceinline__ void rot_mat(float r0, float r1, float r2, float R[9]) {
    // R = Rz2(-r2) * Rx(pi/2 + r1) * Rz(-r0), closed form
    float sa, ca, se, ce, st, ct;
    __sincosf(-r0, &sa, &ca);
    __sincosf(1.57079632679489662f + r1, &se, &ce);
    __sincosf(-r2, &st, &ct);
    R[0] =  ct * ca - st * ce * sa;
    R[1] = -ct * sa - st * ce * ca;
    R[2] =  st * se;
    R[3] =  st * ca + ct * ce * sa;
    R[4] = -st * sa + ct * ce * ca;
    R[5] = -ct * se;
    R[6] =  se * sa;
    R[7] =  se * ca;
    R[8] =  ce;
}

__device__ __forceinline__ void quat(float x0, float x1, float x2, float q[4]) {
    float sr, cr, sp, cp, sy, cy;
    __sincosf(x0 * 0.5f, &sr, &cr);
    __sincosf(x1 * 0.5f, &sp, &cp);
    __sincosf(x2 * 0.5f, &sy, &cy);
    q[0] = sr * cp * cy - cr * sp * sy;
    q[1] = cr * sp * cy + sr * cp * sy;
    q[2] = cr * cp * sy - sr * sp * cy;
    q[3] = cr * cp * cy + sr * sp * sy;
}

__global__ __launch_bounds__(256) void crit_fused_kernel(
    const float* __restrict__ pose_pred, const float* __restrict__ pose_gt,
    const float* __restrict__ trans_pred, const float* __restrict__ trans_gt,
    const float* __restrict__ latent_pred, const float* __restrict__ latent_gt,
    float* __restrict__ out, float* __restrict__ part)
{
    float s0 = 0.0f, s1 = 0.0f, s2 = 0.0f;   // rot_sq, trans_sq, latent_sq partials
    const int b = blockIdx.x;

    if (b < PA_BLOCKS) {
        // ---------- pose + trans phase: 4 rows per thread, float4 loads ----------
        const int t = b * BLOCK + threadIdx.x;            // [0, 131072)
        // pose work first (limits live registers)
        {
            const float4* pp4 = reinterpret_cast<const float4*>(pose_pred);
            const float4* pg4 = reinterpret_cast<const float4*>(pose_gt);
            float4 A0 = pp4[3*t+0], A1 = pp4[3*t+1], A2 = pp4[3*t+2];
            float4 B0 = pg4[3*t+0], B1 = pg4[3*t+1], B2 = pg4[3*t+2];
            float pp[12] = {A0.x,A0.y,A0.z,A0.w, A1.x,A1.y,A1.z,A1.w, A2.x,A2.y,A2.z,A2.w};
            float pg[12] = {B0.x,B0.y,B0.z,B0.w, B1.x,B1.y,B1.z,B1.w, B2.x,B2.y,B2.z,B2.w};
            #pragma unroll
            for (int r = 0; r < 4; ++r) {
                float x0 = pp[3*r]*PI_F, x1 = pp[3*r+1]*PI_F, x2 = pp[3*r+2]*PI_F;
                float y0 = pg[3*r]*PI_F, y1 = pg[3*r+1]*PI_F, y2 = pg[3*r+2]*PI_F;
                float qp[4], qg[4];
                quat(x0, x1, x2, qp);
                quat(y0, y1, y2, qg);
                #pragma unroll
                for (int k = 0; k < 4; ++k) { float d = qp[k] - qg[k]; s0 += d * d; }
                float Rp[9], Rg[9];
                rot_mat(x0, x1, x2, Rp);
                rot_mat(y0, y1, y2, Rg);
                float tr = 0.0f;
                #pragma unroll
                for (int k = 0; k < 9; ++k) tr += Rp[k] * Rg[k];
                float c = fminf(1.0f, fmaxf(-1.0f, (tr - 1.0f) * 0.5f));
                out[3 + 4*t + r] = acosf(c) * (180.0f / PI_F);
            }
        }
        // trans work
        {
            const float4* tp4 = reinterpret_cast<const float4*>(trans_pred);
            const float4* tg4 = reinterpret_cast<const float4*>(trans_gt);
            float4 C0 = tp4[3*t+0], C1 = tp4[3*t+1], C2 = tp4[3*t+2];
            float4 D0 = tg4[3*t+0], D1 = tg4[3*t+1], D2 = tg4[3*t+2];
            float tp[12] = {C0.x,C0.y,C0.z,C0.w, C1.x,C1.y,C1.z,C1.w, C2.x,C2.y,C2.z,C2.w};
            float tg[12] = {D0.x,D0.y,D0.z,D0.w, D1.x,D1.y,D1.z,D1.w, D2.x,D2.y,D2.z,D2.w};
            #pragma unroll
            for (int r = 0; r < 4; ++r) {
                float p0 = tp[3*r], p1 = tp[3*r+1], p2 = tp[3*r+2];
                float g0 = tg[3*r], g1 = tg[3*r+1], g2 = tg[3*r+2];
                float d0 = p0-g0, d1 = p1-g1, d2 = p2-g2;
                s1 += d0*d0 + d1*d1 + d2*d2;
                float a1 = g0*g1 - p0*p1;
                float a2 = g0*g2 - p0*p2;
                out[3 + NROWS + 4*t + r] = sqrtf(a1*a1 + a2*a2) * 100.0f;
            }
        }
    } else {
        // ---------- latent MSE: float4 stream, 2-deep unrolled for MLP ----------
        const int tid  = (b - PA_BLOCKS) * BLOCK + threadIdx.x;
        const int nthr = PB_BLOCKS * BLOCK;
        const float4* __restrict__ lp = reinterpret_cast<const float4*>(latent_pred);
        const float4* __restrict__ lg = reinterpret_cast<const float4*>(latent_gt);
        const int nl4 = NROWS * DLAT / 4;                 // 8388608
        int i = tid;
        for (; i + nthr < nl4; i += 2 * nthr) {
            float4 p0 = lp[i],        g0 = lg[i];
            float4 p1 = lp[i + nthr], g1 = lg[i + nthr];
            float e;
            e = p0.x - g0.x; s2 += e * e;
            e = p0.y - g0.y; s2 += e * e;
            e = p0.z - g0.z; s2 += e * e;
            e = p0.w - g0.w; s2 += e * e;
            e = p1.x - g1.x; s2 += e * e;
            e = p1.y - g1.y; s2 += e * e;
            e = p1.z - g1.z; s2 += e * e;
            e = p1.w - g1.w; s2 += e * e;
        }
        if (i < nl4) {
            float4 p0 = lp[i], g0 = lg[i];
            float e;
            e = p0.x - g0.x; s2 += e * e;
            e = p0.y - g0.y; s2 += e * e;
            e = p0.z - g0.z; s2 += e * e;
            e = p0.w - g0.w; s2 += e * e;
        }
    }

    // ---------- block reduction: wave shuffle then LDS across 4 waves ----------
    #pragma unroll
    for (int off = 32; off > 0; off >>= 1) {
        s0 += __shfl_down(s0, off, 64);
        s1 += __shfl_down(s1, off, 64);
        s2 += __shfl_down(s2, off, 64);
    }
    __shared__ float sp[3][4];
    const int lane = threadIdx.x & 63;
    const int wave = threadIdx.x >> 6;
    if (lane == 0) { sp[0][wave] = s0; sp[1][wave] = s1; sp[2][wave] = s2; }
    __syncthreads();
    if (threadIdx.x == 0) {
        part[0*TOTAL_BLOCKS + b] = sp[0][0] + sp[0][1] + sp[0][2] + sp[0][3];
        part[1*TOTAL_BLOCKS + b] = sp[1][0] + sp[1][1] + sp[1][2] + sp[1][3];
        part[2*TOTAL_BLOCKS + b] = sp[2][0] + sp[2][1] + sp[2][2] + sp[2][3];
    }
}

__global__ __launch_bounds__(256) void finalize_kernel(
    const float* __restrict__ part, float* __restrict__ out)
{
    double a0 = 0.0, a1 = 0.0, a2 = 0.0;
    for (int j = threadIdx.x; j < TOTAL_BLOCKS; j += BLOCK) {
        a0 += (double)part[0*TOTAL_BLOCKS + j];
        a1 += (double)part[1*TOTAL_BLOCKS + j];
        a2 += (double)part[2*TOTAL_BLOCKS + j];
    }
    #pragma unroll
    for (int off = 32; off > 0; off >>= 1) {
        a0 += __shfl_down(a0, off, 64);
        a1 += __shfl_down(a1, off, 64);
        a2 += __shfl_down(a2, off, 64);
    }
    __shared__ double sp[3][4];
    const int lane = threadIdx.x & 63;
    const int wave = threadIdx.x >> 6;
    if (lane == 0) { sp[0][wave] = a0; sp[1][wave] = a1; sp[2][wave] = a2; }
    __syncthreads();
    if (threadIdx.x == 0) {
        double r = sp[0][0] + sp[0][1] + sp[0][2] + sp[0][3];
        double t = sp[1][0] + sp[1][1] + sp[1][2] + sp[1][3];
        double l = sp[2][0] + sp[2][1] + sp[2][2] + sp[2][3];
        out[0] = (float)(r / (4.0  * NROWS));
        out[1] = (float)(t / (3.0  * NROWS));
        out[2] = (float)(l / (64.0 * NROWS));
    }
}

extern "C" void kernel_launch(void* const* d_in, const int* in_sizes, int n_in,
                              void* d_out, int out_size, void* d_ws, size_t ws_size,
                              hipStream_t stream) {
    const float* pose_pred   = (const float*)d_in[0];
    const float* pose_gt     = (const float*)d_in[1];
    const float* trans_pred  = (const float*)d_in[2];
    const float* trans_gt    = (const float*)d_in[3];
    const float* latent_pred = (const float*)d_in[4];
    const float* latent_gt   = (const float*)d_in[5];
    float* out  = (float*)d_out;
    float* part = (float*)d_ws;

    hipLaunchKernelGGL(crit_fused_kernel, dim3(TOTAL_BLOCKS), dim3(BLOCK), 0, stream,
                       pose_pred, pose_gt, trans_pred, trans_gt,
                       latent_pred, latent_gt, out, part);
    hipLaunchKernelGGL(finalize_kernel, dim3(1), dim3(BLOCK), 0, stream, part, out);
}

// Round 3
// 51.520 us; speedup vs baseline: 2.1598x; 1.0442x over previous
//
#include <hip/hip_runtime.h>
#include <math.h>

constexpr int NROWS = 524288;
constexpr float PI_F = 3.14159265358979323846f;
constexpr int BLOCK = 256;
constexpr int PA_BLOCKS = 512;                       // pose/trans + small latent share
constexpr int TOTAL_BLOCKS = 2048;
constexpr int NL4 = NROWS * 64 / 4;                  // 8388608 float4-pairs of latent
constexpr int CA = 2560;                             // latent float4 per PA block (10/thread)
constexpr int CB = 4608;                             // latent float4 per PB block (18/thread)
// exact: 512*2560 + 1536*4608 == 8388608

// d_ws layout (floats): part[0*T+b]=rot, part[1*T+b]=trans, part[2*T+b]=latent

__device__ __forceinline__ void rot_mat(float r0, float r1, float r2, float R[9]) {
    // R = Rz2(-r2) * Rx(pi/2 + r1) * Rz(-r0), closed form
    float sa, ca, se, ce, st, ct;
    __sincosf(-r0, &sa, &ca);
    __sincosf(1.57079632679489662f + r1, &se, &ce);
    __sincosf(-r2, &st, &ct);
    R[0] =  ct * ca - st * ce * sa;
    R[1] = -ct * sa - st * ce * ca;
    R[2] =  st * se;
    R[3] =  st * ca + ct * ce * sa;
    R[4] = -st * sa + ct * ce * ca;
    R[5] = -ct * se;
    R[6] =  se * sa;
    R[7] =  se * ca;
    R[8] =  ce;
}

__device__ __forceinline__ void quat(float x0, float x1, float x2, float q[4]) {
    float sr, cr, sp, cp, sy, cy;
    __sincosf(x0 * 0.5f, &sr, &cr);
    __sincosf(x1 * 0.5f, &sp, &cp);
    __sincosf(x2 * 0.5f, &sy, &cy);
    q[0] = sr * cp * cy - cr * sp * sy;
    q[1] = cr * sp * cy + sr * cp * sy;
    q[2] = cr * cp * sy - sr * sp * cy;
    q[3] = cr * cp * cy + sr * sp * sy;
}

__device__ __forceinline__ void latent_chunk(
    const float4* __restrict__ lp, const float4* __restrict__ lg,
    int start, int count_per_thread, int tix, float& s2)
{
    int i = start + tix;
    // 2-deep MLP unroll; count_per_thread is even (10 or 18)
    for (int j = 0; j < count_per_thread; j += 2, i += 2 * BLOCK) {
        float4 p0 = lp[i],         g0 = lg[i];
        float4 p1 = lp[i + BLOCK], g1 = lg[i + BLOCK];
        float e;
        e = p0.x - g0.x; s2 += e * e;
        e = p0.y - g0.y; s2 += e * e;
        e = p0.z - g0.z; s2 += e * e;
        e = p0.w - g0.w; s2 += e * e;
        e = p1.x - g1.x; s2 += e * e;
        e = p1.y - g1.y; s2 += e * e;
        e = p1.z - g1.z; s2 += e * e;
        e = p1.w - g1.w; s2 += e * e;
    }
}

__global__ __launch_bounds__(256) void crit_fused_kernel(
    const float* __restrict__ pose_pred, const float* __restrict__ pose_gt,
    const float* __restrict__ trans_pred, const float* __restrict__ trans_gt,
    const float* __restrict__ latent_pred, const float* __restrict__ latent_gt,
    float* __restrict__ out, float* __restrict__ part)
{
    float s0 = 0.0f, s1 = 0.0f, s2 = 0.0f;   // rot_sq, trans_sq, latent_sq partials
    const int b = blockIdx.x;
    const int tix = threadIdx.x;
    const float4* __restrict__ lp = reinterpret_cast<const float4*>(latent_pred);
    const float4* __restrict__ lg = reinterpret_cast<const float4*>(latent_gt);

    if (b < PA_BLOCKS) {
        // ---------- pose + trans phase: 4 rows per thread, float4 loads ----------
        const int t = b * BLOCK + tix;                    // [0, 131072)
        {
            const float4* pp4 = reinterpret_cast<const float4*>(pose_pred);
            const float4* pg4 = reinterpret_cast<const float4*>(pose_gt);
            float4 A0 = pp4[3*t+0], A1 = pp4[3*t+1], A2 = pp4[3*t+2];
            float4 B0 = pg4[3*t+0], B1 = pg4[3*t+1], B2 = pg4[3*t+2];
            float pp[12] = {A0.x,A0.y,A0.z,A0.w, A1.x,A1.y,A1.z,A1.w, A2.x,A2.y,A2.z,A2.w};
            float pg[12] = {B0.x,B0.y,B0.z,B0.w, B1.x,B1.y,B1.z,B1.w, B2.x,B2.y,B2.z,B2.w};
            #pragma unroll
            for (int r = 0; r < 4; ++r) {
                float x0 = pp[3*r]*PI_F, x1 = pp[3*r+1]*PI_F, x2 = pp[3*r+2]*PI_F;
                float y0 = pg[3*r]*PI_F, y1 = pg[3*r+1]*PI_F, y2 = pg[3*r+2]*PI_F;
                float qp[4], qg[4];
                quat(x0, x1, x2, qp);
                quat(y0, y1, y2, qg);
                #pragma unroll
                for (int k = 0; k < 4; ++k) { float d = qp[k] - qg[k]; s0 += d * d; }
                float Rp[9], Rg[9];
                rot_mat(x0, x1, x2, Rp);
                rot_mat(y0, y1, y2, Rg);
                float tr = 0.0f;
                #pragma unroll
                for (int k = 0; k < 9; ++k) tr += Rp[k] * Rg[k];
                float c = fminf(1.0f, fmaxf(-1.0f, (tr - 1.0f) * 0.5f));
                out[3 + 4*t + r] = acosf(c) * (180.0f / PI_F);
            }
        }
        {
            const float4* tp4 = reinterpret_cast<const float4*>(trans_pred);
            const float4* tg4 = reinterpret_cast<const float4*>(trans_gt);
            float4 C0 = tp4[3*t+0], C1 = tp4[3*t+1], C2 = tp4[3*t+2];
            float4 D0 = tg4[3*t+0], D1 = tg4[3*t+1], D2 = tg4[3*t+2];
            float tp[12] = {C0.x,C0.y,C0.z,C0.w, C1.x,C1.y,C1.z,C1.w, C2.x,C2.y,C2.z,C2.w};
            float tg[12] = {D0.x,D0.y,D0.z,D0.w, D1.x,D1.y,D1.z,D1.w, D2.x,D2.y,D2.z,D2.w};
            #pragma unroll
            for (int r = 0; r < 4; ++r) {
                float p0 = tp[3*r], p1 = tp[3*r+1], p2 = tp[3*r+2];
                float g0 = tg[3*r], g1 = tg[3*r+1], g2 = tg[3*r+2];
                float d0 = p0-g0, d1 = p1-g1, d2 = p2-g2;
                s1 += d0*d0 + d1*d1 + d2*d2;
                float a1 = g0*g1 - p0*p1;
                float a2 = g0*g2 - p0*p2;
                out[3 + NROWS + 4*t + r] = sqrtf(a1*a1 + a2*a2) * 100.0f;
            }
        }
        // ---------- small latent share ----------
        latent_chunk(lp, lg, b * CA, CA / BLOCK, tix, s2);
    } else {
        // ---------- large latent share ----------
        const int start = PA_BLOCKS * CA + (b - PA_BLOCKS) * CB;
        latent_chunk(lp, lg, start, CB / BLOCK, tix, s2);
    }

    // ---------- block reduction: wave shuffle then LDS across 4 waves ----------
    #pragma unroll
    for (int off = 32; off > 0; off >>= 1) {
        s0 += __shfl_down(s0, off, 64);
        s1 += __shfl_down(s1, off, 64);
        s2 += __shfl_down(s2, off, 64);
    }
    __shared__ float sp[3][4];
    const int lane = threadIdx.x & 63;
    const int wave = threadIdx.x >> 6;
    if (lane == 0) { sp[0][wave] = s0; sp[1][wave] = s1; sp[2][wave] = s2; }
    __syncthreads();
    if (threadIdx.x == 0) {
        part[0*TOTAL_BLOCKS + b] = sp[0][0] + sp[0][1] + sp[0][2] + sp[0][3];
        part[1*TOTAL_BLOCKS + b] = sp[1][0] + sp[1][1] + sp[1][2] + sp[1][3];
        part[2*TOTAL_BLOCKS + b] = sp[2][0] + sp[2][1] + sp[2][2] + sp[2][3];
    }
}

__global__ __launch_bounds__(256) void finalize_kernel(
    const float* __restrict__ part, float* __restrict__ out)
{
    double a0 = 0.0, a1 = 0.0, a2 = 0.0;
    for (int j = threadIdx.x; j < TOTAL_BLOCKS; j += BLOCK) {
        a0 += (double)part[0*TOTAL_BLOCKS + j];
        a1 += (double)part[1*TOTAL_BLOCKS + j];
        a2 += (double)part[2*TOTAL_BLOCKS + j];
    }
    #pragma unroll
    for (int off = 32; off > 0; off >>= 1) {
        a0 += __shfl_down(a0, off, 64);
        a1 += __shfl_down(a1, off, 64);
        a2 += __shfl_down(a2, off, 64);
    }
    __shared__ double sp[3][4];
    const int lane = threadIdx.x & 63;
    const int wave = threadIdx.x >> 6;
    if (lane == 0) { sp[0][wave] = a0; sp[1][wave] = a1; sp[2][wave] = a2; }
    __syncthreads();
    if (threadIdx.x == 0) {
        double r = sp[0][0] + sp[0][1] + sp[0][2] + sp[0][3];
        double t = sp[1][0] + sp[1][1] + sp[1][2] + sp[1][3];
        double l = sp[2][0] + sp[2][1] + sp[2][2] + sp[2][3];
        out[0] = (float)(r / (4.0  * NROWS));
        out[1] = (float)(t / (3.0  * NROWS));
        out[2] = (float)(l / (64.0 * NROWS));
    }
}

extern "C" void kernel_launch(void* const* d_in, const int* in_sizes, int n_in,
                              void* d_out, int out_size, void* d_ws, size_t ws_size,
                              hipStream_t stream) {
    const float* pose_pred   = (const float*)d_in[0];
    const float* pose_gt     = (const float*)d_in[1];
    const float* trans_pred  = (const float*)d_in[2];
    const float* trans_gt    = (const float*)d_in[3];
    const float* latent_pred = (const float*)d_in[4];
    const float* latent_gt   = (const float*)d_in[5];
    float* out  = (float*)d_out;
    float* part = (float*)d_ws;

    hipLaunchKernelGGL(crit_fused_kernel, dim3(TOTAL_BLOCKS), dim3(BLOCK), 0, stream,
                       pose_pred, pose_gt, trans_pred, trans_gt,
                       latent_pred, latent_gt, out, part);
    hipLaunchKernelGGL(finalize_kernel, dim3(1), dim3(BLOCK), 0, stream, part, out);
}